// Round 2
// baseline (414.091 us; speedup 1.0000x reference)
//
#include <hip/hip_runtime.h>
#include <hip/hip_bf16.h>

#define N_Q   25000
#define M_S   25000
#define H_NB  32
#define C_INV 128

typedef unsigned short ushortT;
typedef unsigned short us8 __attribute__((ext_vector_type(8)));
typedef unsigned short us4 __attribute__((ext_vector_type(4)));
typedef short s8v __attribute__((ext_vector_type(8)));
typedef float f32x4 __attribute__((ext_vector_type(4)));

#define GAS __attribute__((address_space(1)))
#define LAS __attribute__((address_space(3)))

__device__ __forceinline__ float b2f(ushortT u) {
    unsigned v = ((unsigned)u) << 16;
    return __builtin_bit_cast(float, v);
}
__device__ __forceinline__ ushortT f2b(float f) {
    __hip_bfloat16 h = __float2bfloat16(f);
    return __builtin_bit_cast(ushortT, h);
}

// ---------------- kernel 1: x fp32 -> bf16 ----------------
__global__ void k_convert_x(const float* __restrict__ x, ushortT* __restrict__ xb) {
    int i = blockIdx.x * 256 + threadIdx.x;
    const int n4 = (M_S * C_INV) / 4;
    if (i >= n4) return;
    float4 v = ((const float4*)x)[i];
    us4 o;
    o[0] = f2b(v.x); o[1] = f2b(v.y); o[2] = f2b(v.z); o[3] = f2b(v.w);
    ((us4*)xb)[i] = o;
}

// ---------------- kernel 2: W fp32 -> fragment-major bf16 ----------------
// elem o = ((ks*8 + db)*64 + lane)*8 + j  holds W[ks*32 + (lane>>4)*8 + j][db*16 + (lane&15)]
__global__ void k_build_wfrag(const float* __restrict__ W, ushortT* __restrict__ wf) {
    int o = blockIdx.x * 256 + threadIdx.x;
    if (o >= 1920 * 128) return;
    int j  = o & 7;
    int l  = (o >> 3) & 63;
    int db = (o >> 9) & 7;
    int ks = o >> 12;
    int r  = ks * 32 + ((l >> 4) * 8) + j;
    int d  = db * 16 + (l & 15);
    wf[o] = f2b(W[r * 128 + d]);
}

// ---------------- stage B chunk (templated on #k this wave owns) ----------------
template<int KA>
__device__ __forceinline__ void do_chunk(int j, const ushortT* s_w, const ushortT* xb,
                                         int q, int cb, int kh, float acc[8][8]) {
    const int xofs = ((cb ^ (q & 7)) * 8);
    #pragma unroll
    for (int hh = 0; hh < 4; ++hh) {
        const int h = j * 4 + hh;
        us8 w8 = *(const us8*)(s_w + q * 520 + h * 16 + kh * 8);
        us8 x8 = *(const us8*)(xb + q * 512 + hh * 128 + xofs);
        float xf[8];
        #pragma unroll
        for (int jj = 0; jj < 8; ++jj) xf[jj] = b2f(x8[jj]);
        #pragma unroll
        for (int a = 0; a < KA; ++a) {
            const float wk = b2f(w8[a]);
            #pragma unroll
            for (int jj = 0; jj < 8; ++jj) acc[a][jj] += wk * xf[jj];
        }
    }
}

template<int KA>
__device__ __forceinline__ void do_stageC(const float acc[8][8], int l, int wv, int kh,
                                          const ushortT* __restrict__ wfrag, float* s_red) {
    s8v afrag[KA];
    #pragma unroll
    for (int a = 0; a < KA; ++a) {
        us8 au;
        #pragma unroll
        for (int jj = 0; jj < 8; ++jj) au[jj] = f2b(acc[a][jj]);
        afrag[a] = __builtin_bit_cast(s8v, au);
    }
    f32x4 part[8];
    #pragma unroll
    for (int db = 0; db < 8; ++db) part[db] = f32x4{0.f, 0.f, 0.f, 0.f};
    #pragma unroll
    for (int a = 0; a < KA; ++a) {
        const int ks = (kh * 8 + a) * 4 + (wv & 3);
        const ushortT* bp = wfrag + (size_t)ks * 4096 + (size_t)l * 8;
        #pragma unroll
        for (int db = 0; db < 8; ++db) {
            s8v b = *(const s8v*)(bp + (size_t)db * 512);
            part[db] = __builtin_amdgcn_mfma_f32_16x16x32_bf16(afrag[a], b, part[db], 0, 0, 0);
        }
    }
    #pragma unroll
    for (int db = 0; db < 8; ++db)
        #pragma unroll
        for (int r = 0; r < 4; ++r)
            atomicAdd(&s_red[((l >> 4) * 4 + r) * 128 + db * 16 + (l & 15)], part[db][r]);
}

// ---------------- kernel 3: fused main ----------------
__global__ __launch_bounds__(512, 4) void k_main(
    const float* __restrict__ qp, const float* __restrict__ sp,
    const int* __restrict__ nb, const float* __restrict__ kp,
    const ushortT* __restrict__ xbf, const ushortT* __restrict__ wfrag,
    float* __restrict__ out)
{
    __shared__ __align__(16) ushortT s_w[16 * 520];      // 16,640 B (q-stride 1040B: bank-quad spread)
    __shared__ int s_idx[16 * 33];                       //  2,112 B (pad -> bank spread)
    __shared__ __align__(16) float s_red[16 * 128];      //  8,192 B
    __shared__ __align__(16) ushortT s_xb[2][8192];      // 32,768 B gather double-buffer

    const int t   = threadIdx.x;
    const int l   = t & 63;
    const int wv  = t >> 6;
    const int blk = blockIdx.x;

    // ---- Stage A: influences + indices ----
    {
        const int q  = t >> 5;
        const int h  = t & 31;
        const int qg = blk * 16 + q;
        const int qc = (qg < N_Q) ? qg : 0;
        const float qx = qp[qc * 3 + 0], qy = qp[qc * 3 + 1], qz = qp[qc * 3 + 2];
        int idx = (qg < N_Q) ? nb[qg * H_NB + h] : M_S;
        const bool valid = ((unsigned)idx < (unsigned)M_S);
        s_idx[q * 33 + h] = valid ? idx : 0;
        float px, py, pz;
        if (valid) { px = sp[idx * 3]; py = sp[idx * 3 + 1]; pz = sp[idx * 3 + 2]; }
        else       { px = 1e6f; py = 1e6f; pz = 1e6f; }
        const float rx = px - qx, ry = py - qy, rz = pz - qz;
        us8 wlo, whi;
        #pragma unroll
        for (int k = 0; k < 15; ++k) {
            const float dx = rx - kp[k * 3 + 0];
            const float dy = ry - kp[k * 3 + 1];
            const float dz = rz - kp[k * 3 + 2];
            const float d2 = dx * dx + dy * dy + dz * dz;
            float w = 1.0f - sqrtf(d2) * (1.0f / 1.2f);
            w = (w > 0.0f) ? w : 0.0f;
            if (k < 8) wlo[k] = f2b(w); else whi[k - 8] = f2b(w);
        }
        whi[7] = 0;
        *(us8*)(s_w + q * 520 + h * 16)     = wlo;
        *(us8*)(s_w + q * 520 + h * 16 + 8) = whi;
        ((float4*)s_red)[t] = float4{0.f, 0.f, 0.f, 0.f};
    }
    __syncthreads();

    // ---- gather staging: chunk = 4 h-slots = 16 KB, source-side XOR swizzle ----
    auto issue_stage = [&](int j, int buf) {
        #pragma unroll
        for (int u = 0; u < 2; ++u) {
            const int i  = wv * 2 + u;                     // q row being staged
            const int hh = l >> 4;
            const int idx = s_idx[i * 33 + j * 4 + hh];
            const ushortT* src = xbf + (size_t)idx * C_INV + (((l & 15) ^ (i & 7)) * 8);
            __builtin_amdgcn_global_load_lds((const GAS unsigned int*)(const void*)src,
                                             (LAS unsigned int*)(void*)(&s_xb[buf][i * 512]),
                                             16, 0, 0);
        }
    };

    issue_stage(0, 0);

    const int q  = l & 15;
    const int cb = (wv & 3) * 4 + (l >> 4);
    const int kh = wv >> 2;

    float acc[8][8];
    #pragma unroll
    for (int a = 0; a < 8; ++a)
        #pragma unroll
        for (int jj = 0; jj < 8; ++jj) acc[a][jj] = 0.f;

    for (int j = 0; j < 8; ++j) {
        __syncthreads();                       // drains vmcnt: stage j complete for all waves
        if (j < 7) issue_stage(j + 1, (j + 1) & 1);
        if (kh == 0) do_chunk<8>(j, s_w, s_xb[j & 1], q, cb, kh, acc);
        else         do_chunk<7>(j, s_w, s_xb[j & 1], q, cb, kh, acc);
    }

    // ---- Stage C: MFMA from register A-fragments, LDS-atomic reduce ----
    if (kh == 0) do_stageC<8>(acc, l, wv, kh, wfrag, s_red);
    else         do_stageC<7>(acc, l, wv, kh, wfrag, s_red);

    __syncthreads();

    // ---- write out ----
    {
        const int qq = t >> 5;
        const int c4 = t & 31;
        const int qg = blk * 16 + qq;
        if (qg < N_Q)
            ((float4*)(out + (size_t)qg * 128))[c4] = ((const float4*)s_red)[qq * 32 + c4];
    }
}

extern "C" void kernel_launch(void* const* d_in, const int* in_sizes, int n_in,
                              void* d_out, int out_size, void* d_ws, size_t ws_size,
                              hipStream_t stream) {
    const float* x  = (const float*)d_in[0];
    const float* qp = (const float*)d_in[1];
    const float* sp = (const float*)d_in[2];
    const int*   nb = (const int*)d_in[3];
    const float* kp = (const float*)d_in[4];
    const float* W  = (const float*)d_in[5];
    float* out = (float*)d_out;

    ushortT* xbf   = (ushortT*)d_ws;                                    // 6.4 MB
    ushortT* wfrag = (ushortT*)((char*)d_ws + (size_t)M_S * C_INV * 2); // 491 KB

    k_convert_x<<<3125, 256, 0, stream>>>(x, xbf);
    k_build_wfrag<<<960, 256, 0, stream>>>(W, wfrag);

    const int nblk = (N_Q + 15) / 16;   // 1563
    k_main<<<nblk, 512, 0, stream>>>(qp, sp, nb, kp, xbf, wfrag, out);
}

// Round 3
// 84.839 us; speedup vs baseline: 4.8809x; 4.8809x over previous
//
#include <hip/hip_runtime.h>
#include <hip/hip_bf16.h>

#define N_Q   25000
#define M_S   25000
#define H_NB  32
#define C_INV 128

typedef unsigned short ushortT;
typedef unsigned short us8 __attribute__((ext_vector_type(8)));
typedef unsigned short us4 __attribute__((ext_vector_type(4)));
typedef short s8v __attribute__((ext_vector_type(8)));
typedef float f32x4 __attribute__((ext_vector_type(4)));

#define GAS __attribute__((address_space(1)))
#define LAS __attribute__((address_space(3)))

__device__ __forceinline__ float b2f(ushortT u) {
    unsigned v = ((unsigned)u) << 16;
    return __builtin_bit_cast(float, v);
}
__device__ __forceinline__ ushortT f2b(float f) {
    __hip_bfloat16 h = __float2bfloat16(f);
    return __builtin_bit_cast(ushortT, h);
}

// ---------------- kernel 1: x fp32 -> bf16 ----------------
__global__ void k_convert_x(const float* __restrict__ x, ushortT* __restrict__ xb) {
    int i = blockIdx.x * 256 + threadIdx.x;
    const int n4 = (M_S * C_INV) / 4;
    if (i >= n4) return;
    float4 v = ((const float4*)x)[i];
    us4 o;
    o[0] = f2b(v.x); o[1] = f2b(v.y); o[2] = f2b(v.z); o[3] = f2b(v.w);
    ((us4*)xb)[i] = o;
}

// ---------------- kernel 2: W fp32 -> fragment-major bf16 ----------------
// elem o = ((ks*8 + db)*64 + lane)*8 + j  holds W[ks*32 + (lane>>4)*8 + j][db*16 + (lane&15)]
__global__ void k_build_wfrag(const float* __restrict__ W, ushortT* __restrict__ wf) {
    int o = blockIdx.x * 256 + threadIdx.x;
    if (o >= 1920 * 128) return;
    int j  = o & 7;
    int l  = (o >> 3) & 63;
    int db = (o >> 9) & 7;
    int ks = o >> 12;
    int r  = ks * 32 + ((l >> 4) * 8) + j;
    int d  = db * 16 + (l & 15);
    wf[o] = f2b(W[r * 128 + d]);
}

// ================= K1: stages A+B (MFMA), writes wf[q][k*128+c] bf16 =================
__global__ __launch_bounds__(256, 4) void k_ab(
    const float* __restrict__ qp, const float* __restrict__ sp,
    const int* __restrict__ nb, const float* __restrict__ kp,
    const ushortT* __restrict__ xbf, ushortT* __restrict__ wf_out)
{
    __shared__ __align__(16) ushortT s_w[16 * 640];   // q*640 + k*40 + h (k-stride 80B) 20,480 B
    __shared__ int s_idx[16 * 33];                    // 2,112 B
    __shared__ __align__(16) ushortT s_x[2][4096];    // row-major 32h x 128c, granule-XOR, 8 KB each

    const int t   = threadIdx.x;
    const int l   = t & 63;
    const int w   = t >> 6;           // wave 0..3
    const int blk = blockIdx.x;

    // ---- Stage A ----
    {
        const int q  = t >> 4;
        const int h2 = t & 15;
        const int qg = blk * 16 + q;
        const int qc = (qg < N_Q) ? qg : 0;
        const float qx = qp[qc * 3 + 0], qy = qp[qc * 3 + 1], qz = qp[qc * 3 + 2];
        #pragma unroll
        for (int i = 0; i < 2; ++i) {
            const int h  = h2 + 16 * i;
            int idx = (qg < N_Q) ? nb[qg * H_NB + h] : M_S;
            const bool valid = ((unsigned)idx < (unsigned)M_S);
            s_idx[q * 33 + h] = valid ? idx : 0;
            float px, py, pz;
            if (valid) { px = sp[idx * 3]; py = sp[idx * 3 + 1]; pz = sp[idx * 3 + 2]; }
            else       { px = 1e6f; py = 1e6f; pz = 1e6f; }
            const float rx = px - qx, ry = py - qy, rz = pz - qz;
            #pragma unroll
            for (int k = 0; k < 15; ++k) {
                const float dx = rx - kp[k * 3 + 0];
                const float dy = ry - kp[k * 3 + 1];
                const float dz = rz - kp[k * 3 + 2];
                const float d2 = dx * dx + dy * dy + dz * dz;
                float wv = 1.0f - sqrtf(d2) * (1.0f / 1.2f);
                wv = (wv > 0.0f) ? wv : 0.0f;
                s_w[q * 640 + k * 40 + h] = f2b(wv);
            }
            s_w[q * 640 + 15 * 40 + h] = 0;   // pad k-row -> zeros
        }
    }
    __syncthreads();

    // ---- staging: row-major [h][128c], granule (h,cg) holds global c-granule cg^(h>>3) ----
    auto stage = [&](int qq, int buf) {
        #pragma unroll
        for (int u = 0; u < 2; ++u) {
            const int G  = (w * 2 + u) * 64 + l;    // 0..511
            const int h  = G >> 4;                  // 0..31
            const int cg = G & 15;
            const int idx = s_idx[qq * 33 + h];
            const int cgs = cg ^ (h >> 3);
            const ushortT* src = xbf + (size_t)idx * C_INV + cgs * 8;
            __builtin_amdgcn_global_load_lds((const GAS unsigned int*)(const void*)src,
                                             (LAS unsigned int*)(void*)(&s_x[buf][(w * 2 + u) * 512]),
                                             16, 0, 0);
        }
    };

    stage(0, 0);

    for (int qq = 0; qq < 16; ++qq) {
        if (qq == 0) __syncthreads();          // buf0 ready (vmcnt drained at barrier)
        if (qq < 15) stage(qq + 1, (qq + 1) & 1);
        const ushortT* xb = s_x[qq & 1];
        const int qg = blk * 16 + qq;

        // A-operand: w[k][h]; lane l: k=l&15, h=(l>>4)*8+j
        s8v af = *(const s8v*)(s_w + qq * 640 + (l & 15) * 40 + (l >> 4) * 8);

        const int g = l >> 4;
        #pragma unroll
        for (int ci = 0; ci < 2; ++ci) {
            const int cc    = w + ci * 4;
            const int cbase = cc * 16 + (l & 15);
            const int cg    = cbase >> 3;
            const int clo   = cbase & 7;
            const ushortT* rb = xb + g * 8 * 128 + ((cg ^ g) * 8) + clo;
            us8 xv;
            #pragma unroll
            for (int j = 0; j < 8; ++j) xv[j] = rb[j * 128];
            s8v bf = __builtin_bit_cast(s8v, xv);
            f32x4 d = __builtin_amdgcn_mfma_f32_16x16x32_bf16(af, bf, (f32x4){0.f,0.f,0.f,0.f}, 0, 0, 0);
            if (qg < N_Q) {
                #pragma unroll
                for (int r = 0; r < 4; ++r) {
                    const int k = g * 4 + r;
                    if (k < 15)
                        wf_out[(size_t)qg * 1920 + k * 128 + cbase] = f2b(d[r]);
                }
            }
        }
        __syncthreads();
    }
}

// ================= K2: out[25000x128] = wf[25000x1920] @ W[1920x128], Q-tile 64 =================
__global__ __launch_bounds__(512, 4) void k_gemm(
    const ushortT* __restrict__ wf, const ushortT* __restrict__ wfrag,
    float* __restrict__ out)
{
    __shared__ __align__(16) ushortT sA[2][4096];   // 8 KB: 64q x 64kc, granule-XOR by q&7
    __shared__ __align__(16) ushortT sB[2][8192];   // 16 KB: fragment-major W slice

    const int t   = threadIdx.x;
    const int l   = t & 63;
    const int w   = t >> 6;          // 0..7
    const int blk = blockIdx.x;
    const int qg  = w >> 2;          // 0..1  (32-query group)
    const int dg  = w & 3;           // 0..3  (32-col group)

    auto stA = [&](int ks, int buf) {
        const int q_l = w * 8 + (l >> 3);
        const int kg  = l & 7;
        int qrow = blk * 64 + q_l;
        if (qrow >= N_Q) qrow = N_Q - 1;
        const ushortT* src = wf + (size_t)qrow * 1920 + ks * 64 + ((kg ^ (q_l & 7)) * 8);
        __builtin_amdgcn_global_load_lds((const GAS unsigned int*)(const void*)src,
                                         (LAS unsigned int*)(void*)(&sA[buf][w * 512]),
                                         16, 0, 0);
    };
    auto stB = [&](int ks, int buf) {
        #pragma unroll
        for (int u = 0; u < 2; ++u) {
            const int gI = (w * 2 + u) * 64 + l;
            const ushortT* src = wfrag + ((size_t)ks * 1024 + gI) * 8;
            __builtin_amdgcn_global_load_lds((const GAS unsigned int*)(const void*)src,
                                             (LAS unsigned int*)(void*)(&sB[buf][(w * 2 + u) * 512]),
                                             16, 0, 0);
        }
    };

    f32x4 acc00 = {0.f,0.f,0.f,0.f}, acc01 = {0.f,0.f,0.f,0.f};
    f32x4 acc10 = {0.f,0.f,0.f,0.f}, acc11 = {0.f,0.f,0.f,0.f};

    stA(0, 0); stB(0, 0);
    __syncthreads();

    for (int ks = 0; ks < 30; ++ks) {
        if (ks < 29) { stA(ks + 1, (ks + 1) & 1); stB(ks + 1, (ks + 1) & 1); }
        const ushortT* A = sA[ks & 1];
        const ushortT* B = sB[ks & 1];
        #pragma unroll
        for (int kk = 0; kk < 2; ++kk) {
            s8v b0 = *(const s8v*)(B + ((kk * 8 + dg * 2 + 0) * 64 + l) * 8);
            s8v b1 = *(const s8v*)(B + ((kk * 8 + dg * 2 + 1) * 64 + l) * 8);
            {
                const int q_l = qg * 32 + 0 * 16 + (l & 15);
                const int kgw = kk * 4 + (l >> 4);
                s8v a = *(const s8v*)(A + q_l * 64 + ((kgw ^ (q_l & 7)) * 8));
                acc00 = __builtin_amdgcn_mfma_f32_16x16x32_bf16(a, b0, acc00, 0, 0, 0);
                acc01 = __builtin_amdgcn_mfma_f32_16x16x32_bf16(a, b1, acc01, 0, 0, 0);
            }
            {
                const int q_l = qg * 32 + 1 * 16 + (l & 15);
                const int kgw = kk * 4 + (l >> 4);
                s8v a = *(const s8v*)(A + q_l * 64 + ((kgw ^ (q_l & 7)) * 8));
                acc10 = __builtin_amdgcn_mfma_f32_16x16x32_bf16(a, b0, acc10, 0, 0, 0);
                acc11 = __builtin_amdgcn_mfma_f32_16x16x32_bf16(a, b1, acc11, 0, 0, 0);
            }
        }
        __syncthreads();
    }

    #pragma unroll
    for (int m = 0; m < 2; ++m) {
        #pragma unroll
        for (int r = 0; r < 4; ++r) {
            const int q = blk * 64 + qg * 32 + m * 16 + (l >> 4) * 4 + r;
            if (q < N_Q) {
                const int d0 = dg * 32 + (l & 15);
                float v0 = (m == 0) ? acc00[r] : acc10[r];
                float v1 = (m == 0) ? acc01[r] : acc11[r];
                out[(size_t)q * 128 + d0]      = v0;
                out[(size_t)q * 128 + d0 + 16] = v1;
            }
        }
    }
}

// ================= fallback: round-1 fused kernel (used if ws too small) =================
__global__ __launch_bounds__(256, 2) void k_main_fb(
    const float* __restrict__ qp, const float* __restrict__ sp,
    const int* __restrict__ nb, const float* __restrict__ kp,
    const ushortT* __restrict__ xbf, const ushortT* __restrict__ wfrag,
    float* __restrict__ out)
{
    __shared__ ushortT s_w[16][32][16];
    __shared__ int s_idx[16][32];
    __shared__ __align__(16) ushortT s_wf[16][1928];

    const int t   = threadIdx.x;
    const int blk = blockIdx.x;

    {
        const int q  = t >> 4;
        const int h0 = t & 15;
        const int qg = blk * 16 + q;
        const int qc = (qg < N_Q) ? qg : 0;
        const float qx = qp[qc * 3 + 0], qy = qp[qc * 3 + 1], qz = qp[qc * 3 + 2];
        #pragma unroll
        for (int i = 0; i < 2; ++i) {
            const int h  = h0 + 16 * i;
            int idx = (qg < N_Q) ? nb[qg * H_NB + h] : M_S;
            const bool valid = ((unsigned)idx < (unsigned)M_S);
            s_idx[q][h] = valid ? idx : 0;
            float px, py, pz;
            if (valid) { px = sp[idx * 3]; py = sp[idx * 3 + 1]; pz = sp[idx * 3 + 2]; }
            else       { px = 1e6f; py = 1e6f; pz = 1e6f; }
            const float rx = px - qx, ry = py - qy, rz = pz - qz;
            #pragma unroll
            for (int k = 0; k < 15; ++k) {
                const float dx = rx - kp[k * 3 + 0];
                const float dy = ry - kp[k * 3 + 1];
                const float dz = rz - kp[k * 3 + 2];
                const float d2 = dx * dx + dy * dy + dz * dz;
                float wv = 1.0f - sqrtf(d2) * (1.0f / 1.2f);
                wv = (wv > 0.0f) ? wv : 0.0f;
                s_w[q][h][k] = f2b(wv);
            }
            s_w[q][h][15] = 0;
        }
    }
    __syncthreads();

    {
        const int q  = t >> 4;
        const int c0 = (t & 15) * 8;
        float acc[15][8];
        #pragma unroll
        for (int k = 0; k < 15; ++k)
            #pragma unroll
            for (int j = 0; j < 8; ++j) acc[k][j] = 0.0f;

        int idx0 = s_idx[q][0];
        us8 xv = *(const us8*)(xbf + (size_t)idx0 * C_INV + c0);
        for (int h = 0; h < 32; ++h) {
            const us8 xc = xv;
            if (h < 31) {
                int idn = s_idx[q][h + 1];
                xv = *(const us8*)(xbf + (size_t)idn * C_INV + c0);
            }
            const us8 w0 = *(const us8*)&s_w[q][h][0];
            const us8 w1 = *(const us8*)&s_w[q][h][8];
            float xf[8];
            #pragma unroll
            for (int j = 0; j < 8; ++j) xf[j] = b2f(xc[j]);
            #pragma unroll
            for (int k = 0; k < 15; ++k) {
                const float wk = b2f((k < 8) ? w0[k] : w1[k - 8]);
                #pragma unroll
                for (int j = 0; j < 8; ++j) acc[k][j] += wk * xf[j];
            }
        }
        #pragma unroll
        for (int k = 0; k < 15; ++k) {
            us8 o;
            #pragma unroll
            for (int j = 0; j < 8; ++j) o[j] = f2b(acc[k][j]);
            *(us8*)&s_wf[q][k * C_INV + c0] = o;
        }
    }
    __syncthreads();

    {
        const int lane = t & 63;
        const int wv   = t >> 6;
        const int db0  = wv * 2;
        const int arow = lane & 15;
        const int kofs = (lane >> 4) * 8;
        f32x4 acc0 = {0.f, 0.f, 0.f, 0.f};
        f32x4 acc1 = {0.f, 0.f, 0.f, 0.f};
        #pragma unroll 4
        for (int ks = 0; ks < 60; ++ks) {
            s8v a  = *(const s8v*)&s_wf[arow][ks * 32 + kofs];
            s8v b0 = *(const s8v*)(wfrag + ((size_t)(ks * 8 + db0) * 64 + lane) * 8);
            s8v b1 = *(const s8v*)(wfrag + ((size_t)(ks * 8 + db0 + 1) * 64 + lane) * 8);
            acc0 = __builtin_amdgcn_mfma_f32_16x16x32_bf16(a, b0, acc0, 0, 0, 0);
            acc1 = __builtin_amdgcn_mfma_f32_16x16x32_bf16(a, b1, acc1, 0, 0, 0);
        }
        #pragma unroll
        for (int r = 0; r < 4; ++r) {
            const int q  = (lane >> 4) * 4 + r;
            const int qg = blk * 16 + q;
            if (qg < N_Q) {
                out[(size_t)qg * 128 + db0 * 16 + (lane & 15)]       = acc0[r];
                out[(size_t)qg * 128 + (db0 + 1) * 16 + (lane & 15)] = acc1[r];
            }
        }
    }
}

extern "C" void kernel_launch(void* const* d_in, const int* in_sizes, int n_in,
                              void* d_out, int out_size, void* d_ws, size_t ws_size,
                              hipStream_t stream) {
    const float* x  = (const float*)d_in[0];
    const float* qp = (const float*)d_in[1];
    const float* sp = (const float*)d_in[2];
    const int*   nb = (const int*)d_in[3];
    const float* kp = (const float*)d_in[4];
    const float* W  = (const float*)d_in[5];
    float* out = (float*)d_out;

    const size_t xbf_b   = (size_t)M_S * C_INV * 2;        // 6,400,000
    const size_t wfrag_b = (size_t)1920 * 128 * 2;         // 491,520
    const size_t wf_b    = (size_t)25024 * 1920 * 2;       // ~96.1 MB

    ushortT* xbf   = (ushortT*)d_ws;
    ushortT* wfrag = (ushortT*)((char*)d_ws + xbf_b);
    ushortT* wfbuf = (ushortT*)((char*)d_ws + xbf_b + wfrag_b);

    k_convert_x<<<3125, 256, 0, stream>>>(x, xbf);
    k_build_wfrag<<<960, 256, 0, stream>>>(W, wfrag);

    const int nblk = (N_Q + 15) / 16;   // 1563
    if (ws_size >= xbf_b + wfrag_b + wf_b) {
        k_ab<<<nblk, 256, 0, stream>>>(qp, sp, nb, kp, xbf, wfbuf);
        k_gemm<<<(N_Q + 63) / 64, 512, 0, stream>>>(wfbuf, wfrag, out);
    } else {
        k_main_fb<<<nblk, 256, 0, stream>>>(qp, sp, nb, kp, xbf, wfrag, out);
    }
}